// Round 14
// baseline (734.143 us; speedup 1.0000x reference)
//
#include <hip/hip_runtime.h>

#define BB 1024
#define TT 512
#define CC 41
#define BPS 48   // bp row stride (41 used + pad)

__device__ __forceinline__ float rlanef(float xv, int l) {
    return __int_as_float(__builtin_amdgcn_readlane(__float_as_int(xv), l));
}

// Phase A: argmax over p in [0,21). 21 leaves, 20 combines, contiguous blocks,
// keep-left on strict > == first-occurrence.
__device__ __forceinline__ void halfA(float sc, float em, const float (&tr)[CC],
                                      float& mv, int& iv) {
    float v[21]; int ix[21];
    #pragma unroll
    for (int p = 0; p < 21; ++p) {
        v[p] = (rlanef(sc, p) + tr[p]) + em;   // exact ref op order
        ix[p] = p;
    }
#define CMB(i, j) if (v[(j)] > v[(i)]) { v[(i)] = v[(j)]; ix[(i)] = ix[(j)]; }
    #pragma unroll
    for (int i = 0; i < 10; ++i) { CMB(2 * i, 2 * i + 1) }   // blocks of 2
    #pragma unroll
    for (int i = 0; i < 5; ++i)  { CMB(4 * i, 4 * i + 2) }   // blocks of 4
    CMB(0, 4) CMB(8, 12) CMB(16, 20)                         // [0..7][8..15][16..20]
    CMB(0, 8)                                                // [0..15]
    CMB(0, 16)                                               // [0..20]
#undef CMB
    mv = v[0]; iv = ix[0];
}

// Phase B: argmax over p in [21,41). 20 leaves, 19 combines.
__device__ __forceinline__ void halfB(float sc, float em, const float (&tr)[CC],
                                      float& mv, int& iv) {
    float v[20]; int ix[20];
    #pragma unroll
    for (int p = 0; p < 20; ++p) {
        v[p] = (rlanef(sc, 21 + p) + tr[21 + p]) + em;
        ix[p] = 21 + p;
    }
#define CMB(i, j) if (v[(j)] > v[(i)]) { v[(i)] = v[(j)]; ix[(i)] = ix[(j)]; }
    #pragma unroll
    for (int i = 0; i < 10; ++i) { CMB(2 * i, 2 * i + 1) }   // blocks of 2
    #pragma unroll
    for (int i = 0; i < 5; ++i)  { CMB(4 * i, 4 * i + 2) }   // blocks of 4
    CMB(0, 4) CMB(8, 12)                                     // [0..7][8..15]; [16..19] at 16
    CMB(0, 8)                                                // [0..15]
    CMB(0, 16)                                               // [0..19]
#undef CMB
    mv = v[0]; iv = ix[0];
}

__global__ __launch_bounds__(64, 1) void crf_viterbi_kernel(
    const float* __restrict__ x,
    const float* __restrict__ start_t,
    const float* __restrict__ end_t,
    const float* __restrict__ trans,
    int* __restrict__ out)   // harness reads out_size int32 elements
{
    __shared__ unsigned char bp0_lds[(TT - 1) * BPS];
    __shared__ unsigned char bp1_lds[(TT - 1) * BPS];
    __shared__ int tags0_lds[TT];
    __shared__ int tags1_lds[TT];

    const int lane = threadIdx.x;
    const int c = (lane < CC) ? lane : (CC - 1);   // clamp for safe loads

    // trans column c (shared by both streams)
    float trans_reg[CC];
    #pragma unroll
    for (int p = 0; p < CC; ++p) trans_reg[p] = trans[p * CC + c];

    const int b0 = blockIdx.x * 2;
    const int b1 = b0 + 1;
    const float* xb0 = x + (size_t)b0 * TT * CC;
    const float* xb1 = x + (size_t)b1 * TT * CC;

    // t = 0: score0 = start_transitions + x[:,0]   (exact ref op order)
    float sc0 = start_t[c] + xb0[c];
    float sc1 = start_t[c] + xb1[c];

    // 3-deep emit prefetch per stream
    float e0a = xb0[1 * CC + c], e0b = xb0[2 * CC + c], e0c = xb0[3 * CC + c];
    float e1a = xb1[1 * CC + c], e1b = xb1[2 * CC + c], e1c = xb1[3 * CC + c];

    for (int t = 1; t < TT; ++t) {
        const int tf = (t + 3 < TT) ? (t + 3) : (TT - 1);
        const float f0 = xb0[(size_t)tf * CC + c];
        const float f1 = xb1[(size_t)tf * CC + c];

        // Two independent streams; half-trees bound peak register pressure.
        float mA0, mA1, mB0, mB1;
        int   iA0, iA1, iB0, iB1;
        halfA(sc0, e0a, trans_reg, mA0, iA0);
        halfA(sc1, e1a, trans_reg, mA1, iA1);
        halfB(sc0, e0a, trans_reg, mB0, iB0);
        halfB(sc1, e1a, trans_reg, mB1, iB1);

        // Merge: A indices all < B indices -> keep A on tie == first occurrence.
        if (mB0 > mA0) { mA0 = mB0; iA0 = iB0; }
        if (mB1 > mA1) { mA1 = mB1; iA1 = iB1; }

        sc0 = mA0;
        sc1 = mA1;
        if (lane < BPS) {   // pad cols 41..47 never read
            bp0_lds[(t - 1) * BPS + lane] = (unsigned char)iA0;
            bp1_lds[(t - 1) * BPS + lane] = (unsigned char)iA1;
        }

        e0a = e0b; e0b = e0c; e0c = f0;
        e1a = e1b; e1b = e1c; e1c = f1;
    }

    // final = score + end_transitions   (exact ref op order)
    const float fin0 = sc0 + end_t[c];
    const float fin1 = sc1 + end_t[c];

    // Final argmax (first occurrence), two interleaved readlane scans.
    float bv0 = rlanef(fin0, 0); int tag0 = 0;
    float bv1 = rlanef(fin1, 0); int tag1 = 0;
    #pragma unroll
    for (int i = 1; i < CC; ++i) {
        const float q0 = rlanef(fin0, i);
        const float q1 = rlanef(fin1, i);
        if (q0 > bv0) { bv0 = q0; tag0 = i; }
        if (q1 > bv1) { bv1 = q1; tag1 = i; }
    }

    __syncthreads();   // drain bp writes (single wave: cheap)

    // Pipelined backtrack (proven R10/R13): batch-load 16 rows per stream,
    // resolve via readlane chains (uniform index); two chains interleave.
    if (lane == 0) { tags0_lds[TT - 1] = tag0; tags1_lds[TT - 1] = tag1; }
    for (int g = 31; g >= 0; --g) {
        const int base = g * 16;
        unsigned int r0[16], r1[16];
        #pragma unroll
        for (int j = 0; j < 16; ++j) {
            const int r = base + j;
            const int rr = (r < TT - 1) ? r : (TT - 2);   // clamp row 511 read
            r0[j] = (unsigned int)bp0_lds[rr * BPS + lane];
            r1[j] = (unsigned int)bp1_lds[rr * BPS + lane];
        }
        #pragma unroll
        for (int j = 15; j >= 0; --j) {
            const int r = base + j;          // row r maps tag@r+1 -> tag@r
            if (r < TT - 1) {
                tag0 = (int)__builtin_amdgcn_readlane((int)r0[j], tag0);
                tag1 = (int)__builtin_amdgcn_readlane((int)r1[j], tag1);
                if (lane == 0) { tags0_lds[r] = tag0; tags1_lds[r] = tag1; }
            }
        }
    }
    __syncthreads();

    // coalesced output writes
    int* ob0 = out + (size_t)b0 * TT;
    int* ob1 = out + (size_t)b1 * TT;
    #pragma unroll
    for (int i = 0; i < TT / 64; ++i) {
        ob0[lane + 64 * i] = tags0_lds[lane + 64 * i];
        ob1[lane + 64 * i] = tags1_lds[lane + 64 * i];
    }
}

extern "C" void kernel_launch(void* const* d_in, const int* in_sizes, int n_in,
                              void* d_out, int out_size, void* d_ws, size_t ws_size,
                              hipStream_t stream) {
    (void)in_sizes; (void)n_in; (void)d_ws; (void)ws_size; (void)out_size;
    const float* x       = (const float*)d_in[0];
    const float* start_t = (const float*)d_in[1];
    const float* end_t   = (const float*)d_in[2];
    const float* trans   = (const float*)d_in[3];
    int* out = (int*)d_out;

    crf_viterbi_kernel<<<dim3(BB / 2), dim3(64), 0, stream>>>(x, start_t, end_t, trans, out);
}

// Round 15
// 264.415 us; speedup vs baseline: 2.7765x; 2.7765x over previous
//
#include <hip/hip_runtime.h>

#define BB 1024
#define TT 512
#define CC 41

__device__ __forceinline__ float rlanef(float xv, int l) {
    return __int_as_float(__builtin_amdgcn_readlane(__float_as_int(xv), l));
}

__global__ __launch_bounds__(64) void crf_viterbi_kernel(
    const float* __restrict__ x,
    const float* __restrict__ start_t,
    const float* __restrict__ end_t,
    const float* __restrict__ trans,
    int* __restrict__ out)   // harness reads out_size int32 elements
{
    __shared__ unsigned char bp_lds[TT * CC];   // rows 0..510 used; 511 = read pad
    __shared__ int tags_lds[TT];

    const int lane = threadIdx.x;
    const bool active = lane < CC;
    const int c = active ? lane : (CC - 1);   // clamp for safe loads

    // trans column c in registers (coalesced: lanes contiguous per p)
    float trans_reg[CC];
    #pragma unroll
    for (int p = 0; p < CC; ++p) trans_reg[p] = trans[p * CC + c];

    const float* xb = x + (size_t)blockIdx.x * TT * CC;

    // t = 0: score0 = start_transitions + x[:,0]   (exact ref op order)
    float myscore = start_t[c] + xb[c];

    // 2-deep emit prefetch pipeline
    float emit_cur = xb[1 * CC + c];
    float emit_nxt = xb[2 * CC + c];

    for (int t = 1; t < TT; ++t) {
        const int tf = (t + 2 < TT) ? (t + 2) : (TT - 1);
        const float emit_fut = xb[(size_t)tf * CC + c];

        // Broadcast prev scores via readlane; exact ref op order:
        // (score + trans) + emit. All 41 candidates independent.
        float v[CC];
        int  ix[CC];
        #pragma unroll
        for (int p = 0; p < CC; ++p) {
            const float sp = rlanef(myscore, p);
            v[p]  = (sp + trans_reg[p]) + emit_cur;
            ix[p] = p;
        }

        // Segment-tree argmax over contiguous blocks (depth 6): keep-left on
        // strict > == jnp.argmax first-occurrence.
#define COMBINE(i, j) do { \
            if (v[(j)] > v[(i)]) { v[(i)] = v[(j)]; ix[(i)] = ix[(j)]; } \
        } while (0)
        #pragma unroll
        for (int i = 0; i < 20; ++i) COMBINE(2 * i, 2 * i + 1);   // [2i,2i+1]
        #pragma unroll
        for (int i = 0; i < 10; ++i) COMBINE(4 * i, 4 * i + 2);   // [4i..4i+3]
        #pragma unroll
        for (int i = 0; i < 5; ++i)  COMBINE(8 * i, 8 * i + 4);   // [8i..8i+7]
        COMBINE(0, 8);    // [0..15]
        COMBINE(16, 24);  // [16..31]
        COMBINE(0, 16);   // [0..31]
        COMBINE(32, 40);  // [32..40]
        COMBINE(0, 32);   // [0..40]
#undef COMBINE

        myscore = v[0];
        if (active) bp_lds[(t - 1) * CC + lane] = (unsigned char)ix[0];

        emit_cur = emit_nxt;
        emit_nxt = emit_fut;
    }

    // final = score + end_transitions   (exact ref op order)
    const float fin = myscore + end_t[c];

    // Final argmax over tags (first occurrence), uniform readlane scan.
    float bestv = rlanef(fin, 0);
    int tag = 0;
    #pragma unroll
    for (int i = 1; i < CC; ++i) {
        const float vi = rlanef(fin, i);
        if (vi > bestv) { bestv = vi; tag = i; }
    }

    __syncthreads();   // drain bp_lds writes (single wave: cheap)

    // Pipelined backtrack (proven R10): row addresses are tag-independent, so
    // batch-load 16 rows (lane c holds bp[r][c]), then resolve via readlane
    // chain (uniform SGPR index). 32 batch waits instead of 511 dependent
    // LDS byte loads.
    if (lane == 0) tags_lds[TT - 1] = tag;   // tag at time 511
    for (int g = 31; g >= 0; --g) {
        const int base = g * 16;
        unsigned int rowv[16];
        #pragma unroll
        for (int j = 0; j < 16; ++j)
            rowv[j] = (unsigned int)bp_lds[(base + j) * CC + c];
        #pragma unroll
        for (int j = 15; j >= 0; --j) {
            const int r = base + j;          // row r maps tag@r+1 -> tag@r
            if (r < TT - 1) {
                tag = (int)__builtin_amdgcn_readlane((int)rowv[j], tag);
                if (lane == 0) tags_lds[r] = tag;
            }
        }
    }
    __syncthreads();

    // coalesced output write: one int32 per tag
    int* ob = out + (size_t)blockIdx.x * TT;
    #pragma unroll
    for (int i = 0; i < TT / 64; ++i) ob[lane + 64 * i] = tags_lds[lane + 64 * i];
}

extern "C" void kernel_launch(void* const* d_in, const int* in_sizes, int n_in,
                              void* d_out, int out_size, void* d_ws, size_t ws_size,
                              hipStream_t stream) {
    (void)in_sizes; (void)n_in; (void)d_ws; (void)ws_size; (void)out_size;
    const float* x       = (const float*)d_in[0];
    const float* start_t = (const float*)d_in[1];
    const float* end_t   = (const float*)d_in[2];
    const float* trans   = (const float*)d_in[3];
    int* out = (int*)d_out;

    crf_viterbi_kernel<<<dim3(BB), dim3(64), 0, stream>>>(x, start_t, end_t, trans, out);
}